// Round 1
// baseline (3753.292 us; speedup 1.0000x reference)
//
#include <hip/hip_runtime.h>
#include <stdint.h>

typedef __bf16 bf16x8 __attribute__((ext_vector_type(8)));
typedef float f32x4 __attribute__((ext_vector_type(4)));

__device__ __forceinline__ float bf2f(unsigned short u) {
  union { uint32_t i; float f; } v; v.i = ((uint32_t)u) << 16; return v.f;
}
__device__ __forceinline__ unsigned short f2bf(float f) {
  union { uint32_t i; float f; } v; v.f = f;
  uint32_t u = v.i;
  return (unsigned short)((u + 0x7fffu + ((u >> 16) & 1u)) >> 16);
}
__device__ __forceinline__ float sigm(float x) { return 1.0f / (1.0f + __expf(-x)); }
__device__ __forceinline__ float tanh_f(float x) { return 1.0f - 2.0f / (__expf(2.0f * x) + 1.0f); }

__device__ __forceinline__ ushort4 cvt4(float4 a) {
  ushort4 o; o.x = f2bf(a.x); o.y = f2bf(a.y); o.z = f2bf(a.z); o.w = f2bf(a.w); return o;
}

// ---------- fp32 -> bf16 bulk convert, 8 elems/thread ----------
__global__ void k_f2bf(const float* __restrict__ src, unsigned short* __restrict__ dst, long long n8) {
  long long t = (long long)blockIdx.x * blockDim.x + threadIdx.x;
  if (t >= n8) return;
  const float4* s = (const float4*)src + t * 2;
  float4 a = s[0], b = s[1];
  ((ushort4*)dst)[t * 2]     = cvt4(a);
  ((ushort4*)dst)[t * 2 + 1] = cvt4(b);
}

// ---------- build Wcat[1536][1024] = [U_iou | W_iou] in bf16 ----------
__global__ void k_build_wcat(const float* __restrict__ U_iou, const float* __restrict__ W_iou,
                             unsigned short* __restrict__ wcat, int total8) {
  int t = blockIdx.x * blockDim.x + threadIdx.x;
  if (t >= total8) return;
  int row = t >> 7;      // 128 chunks of 8 per 1024-wide row
  int ch  = t & 127;
  const float* src = (ch < 64) ? (U_iou + (size_t)row * 512 + ch * 8)
                               : (W_iou + (size_t)row * 512 + (ch - 64) * 8);
  const float4* s = (const float4*)src;
  unsigned short* d = wcat + (size_t)row * 1024 + ch * 8;
  ((ushort4*)d)[0] = cvt4(s[0]);
  ((ushort4*)d)[1] = cvt4(s[1]);
}

// ---------- edge scatter: h_tilde += h[ch], c_red += f*c[ch], deg[p]++ ----------
__global__ void k_scatter(const float* __restrict__ h, const float* __restrict__ c,
                          const unsigned short* __restrict__ g,
                          const int* __restrict__ child, const int* __restrict__ parent,
                          float* __restrict__ h_tilde, float* __restrict__ c_red,
                          int* __restrict__ deg, int M) {
  int e = blockIdx.x * 4 + (threadIdx.x >> 6);
  if (e >= M) return;
  int ln = threadIdx.x & 63;
  int ch = child[e];
  int p  = parent[e];
  if (ln == 0) atomicAdd(&deg[p], 1);
  size_t cb = (size_t)ch * 512;
  size_t pb = (size_t)p  * 512;
#pragma unroll
  for (int r = 0; r < 2; ++r) {
    int j = ln * 8 + r * 4;
    float4  hv = *(const float4*)(h + cb + j);
    float4  cv = *(const float4*)(c + cb + j);
    ushort4 gv = *(const ushort4*)(g + cb + j);
    unsafeAtomicAdd(&h_tilde[pb + j + 0], hv.x);
    unsafeAtomicAdd(&h_tilde[pb + j + 1], hv.y);
    unsafeAtomicAdd(&h_tilde[pb + j + 2], hv.z);
    unsafeAtomicAdd(&h_tilde[pb + j + 3], hv.w);
    unsafeAtomicAdd(&c_red[pb + j + 0], bf2f(gv.x) * cv.x);
    unsafeAtomicAdd(&c_red[pb + j + 1], bf2f(gv.y) * cv.y);
    unsafeAtomicAdd(&c_red[pb + j + 2], bf2f(gv.z) * cv.z);
    unsafeAtomicAdd(&c_red[pb + j + 3], bf2f(gv.w) * cv.w);
  }
}

// ---------- build Z[n] = has_child ? [h_tilde, 0] : [0, x]  (bf16, K=1024) ----------
__global__ void k_build_z(const float* __restrict__ h_tilde, const float* __restrict__ x,
                          const int* __restrict__ deg,
                          unsigned short* __restrict__ Z, int Nn) {
  long long t = (long long)blockIdx.x * blockDim.x + threadIdx.x;
  int n = (int)(t >> 6);
  if (n >= Nn) return;
  int j = ((int)t & 63) * 8;
  bool has = deg[n] > 0;
  size_t zb = (size_t)n * 1024;
  ushort4 z0 = {0, 0, 0, 0}, z1 = {0, 0, 0, 0};
  if (has) {
    const float4* s = (const float4*)(h_tilde + (size_t)n * 512 + j);
    z0 = cvt4(s[0]); z1 = cvt4(s[1]);
  }
  ((ushort4*)(Z + zb + j))[0] = z0;
  ((ushort4*)(Z + zb + j))[1] = z1;
  z0 = (ushort4){0, 0, 0, 0}; z1 = (ushort4){0, 0, 0, 0};
  if (!has) {
    const float4* s = (const float4*)(x + (size_t)n * 512 + j);
    z0 = cvt4(s[0]); z1 = cvt4(s[1]);
  }
  ((ushort4*)(Z + zb + 512 + j))[0] = z0;
  ((ushort4*)(Z + zb + 512 + j))[1] = z1;
}

// ---------- bf16 GEMM, C = act(A @ Bt^T + bias), m97-style 128x128x32 ----------
// A: [Mrows][K] bf16 row-major.  Bt: [Ncols][K] bf16 row-major (B-transposed input).
// C: [Mrows][ldc] bf16.  ACT: 0 = none, 1 = sigmoid.
template <int ACT>
__global__ __launch_bounds__(256)
void k_gemm_bt(const unsigned short* __restrict__ A, int K,
               const unsigned short* __restrict__ Bt,
               const float* __restrict__ bias,
               unsigned short* __restrict__ C, int ldc, int Mrows) {
  __shared__ __align__(16) unsigned short ldsA[128 * 32];
  __shared__ __align__(16) unsigned short ldsB[128 * 32];
  const int tid = threadIdx.x;
  const int wv = tid >> 6, ln = tid & 63;
  const int wr = wv >> 1, wc = wv & 1;
  const int row0 = blockIdx.y * 128;
  const int col0 = blockIdx.x * 128;

  f32x4 acc[4][4] = {};

  for (int k0 = 0; k0 < K; k0 += 32) {
#pragma unroll
    for (int rep = 0; rep < 2; ++rep) {
      int cidx = rep * 256 + wv * 64 + ln;   // 16B chunk id, 0..511
      int r  = cidx >> 2;                    // tile row 0..127
      int kp = (cidx & 3) * 8;               // k sub-offset
      int ga = row0 + r; if (ga > Mrows - 1) ga = Mrows - 1;
      const unsigned short* srcA = A + (size_t)ga * K + k0 + kp;
      __builtin_amdgcn_global_load_lds(
          (const __attribute__((address_space(1))) void*)(void*)srcA,
          (__attribute__((address_space(3))) void*)(ldsA + (rep * 256 + wv * 64) * 8),
          16, 0, 0);
      const unsigned short* srcB = Bt + (size_t)(col0 + r) * K + k0 + kp;
      __builtin_amdgcn_global_load_lds(
          (const __attribute__((address_space(1))) void*)(void*)srcB,
          (__attribute__((address_space(3))) void*)(ldsB + (rep * 256 + wv * 64) * 8),
          16, 0, 0);
    }
    __syncthreads();

    bf16x8 af[4], bfr[4];
#pragma unroll
    for (int mi = 0; mi < 4; ++mi)
      af[mi] = *(const bf16x8*)(ldsA + (wr * 64 + mi * 16 + (ln & 15)) * 32 + (ln >> 4) * 8);
#pragma unroll
    for (int ni = 0; ni < 4; ++ni)
      bfr[ni] = *(const bf16x8*)(ldsB + (wc * 64 + ni * 16 + (ln & 15)) * 32 + (ln >> 4) * 8);
#pragma unroll
    for (int mi = 0; mi < 4; ++mi)
#pragma unroll
      for (int ni = 0; ni < 4; ++ni)
        acc[mi][ni] = __builtin_amdgcn_mfma_f32_16x16x32_bf16(af[mi], bfr[ni], acc[mi][ni], 0, 0, 0);
    __syncthreads();
  }

#pragma unroll
  for (int mi = 0; mi < 4; ++mi) {
#pragma unroll
    for (int ni = 0; ni < 4; ++ni) {
      int col = col0 + wc * 64 + ni * 16 + (ln & 15);
      float bv = bias[col];
#pragma unroll
      for (int r = 0; r < 4; ++r) {
        int m = row0 + wr * 64 + mi * 16 + (ln >> 4) * 4 + r;
        if (m < Mrows) {
          float v = acc[mi][ni][r] + bv;
          if (ACT == 1) v = sigm(v);
          C[(size_t)m * ldc + col] = f2bf(v);
        }
      }
    }
  }
}

// ---------- LSTM epilogue: read iou(bf16) + c_red, write h_new, c_new ----------
__global__ void k_epilogue(const unsigned short* __restrict__ iou,
                           float* __restrict__ out, int Nn) {
  long long t = (long long)blockIdx.x * blockDim.x + threadIdx.x;
  int n = (int)(t >> 6);
  if (n >= Nn) return;
  int j = ((int)t & 63) * 8;
  size_t ib = (size_t)n * 1536;
  ushort4 iv0 = *(const ushort4*)(iou + ib + j);
  ushort4 iv1 = *(const ushort4*)(iou + ib + j + 4);
  ushort4 ov0 = *(const ushort4*)(iou + ib + 512 + j);
  ushort4 ov1 = *(const ushort4*)(iou + ib + 512 + j + 4);
  ushort4 uv0 = *(const ushort4*)(iou + ib + 1024 + j);
  ushort4 uv1 = *(const ushort4*)(iou + ib + 1024 + j + 4);
  size_t cb = (size_t)Nn * 512 + (size_t)n * 512 + j;
  float4 cr0 = *(const float4*)(out + cb);
  float4 cr1 = *(const float4*)(out + cb + 4);

  float iarr[8] = {bf2f(iv0.x), bf2f(iv0.y), bf2f(iv0.z), bf2f(iv0.w),
                   bf2f(iv1.x), bf2f(iv1.y), bf2f(iv1.z), bf2f(iv1.w)};
  float oarr[8] = {bf2f(ov0.x), bf2f(ov0.y), bf2f(ov0.z), bf2f(ov0.w),
                   bf2f(ov1.x), bf2f(ov1.y), bf2f(ov1.z), bf2f(ov1.w)};
  float uarr[8] = {bf2f(uv0.x), bf2f(uv0.y), bf2f(uv0.z), bf2f(uv0.w),
                   bf2f(uv1.x), bf2f(uv1.y), bf2f(uv1.z), bf2f(uv1.w)};
  float carr[8] = {cr0.x, cr0.y, cr0.z, cr0.w, cr1.x, cr1.y, cr1.z, cr1.w};
  float hn[8], cn[8];
#pragma unroll
  for (int q = 0; q < 8; ++q) {
    float cc = sigm(iarr[q]) * tanh_f(uarr[q]) + carr[q];
    cn[q] = cc;
    hn[q] = sigm(oarr[q]) * tanh_f(cc);
  }
  size_t hb = (size_t)n * 512 + j;
  *(float4*)(out + hb)     = make_float4(hn[0], hn[1], hn[2], hn[3]);
  *(float4*)(out + hb + 4) = make_float4(hn[4], hn[5], hn[6], hn[7]);
  *(float4*)(out + cb)     = make_float4(cn[0], cn[1], cn[2], cn[3]);
  *(float4*)(out + cb + 4) = make_float4(cn[4], cn[5], cn[6], cn[7]);
}

extern "C" void kernel_launch(void* const* d_in, const int* in_sizes, int n_in,
                              void* d_out, int out_size, void* d_ws, size_t ws_size,
                              hipStream_t stream) {
  const float* x     = (const float*)d_in[0];
  const float* h     = (const float*)d_in[1];
  const float* c     = (const float*)d_in[2];
  const int* child   = (const int*)d_in[3];
  const int* parent  = (const int*)d_in[4];
  const float* W_iou = (const float*)d_in[5];
  const float* U_iou = (const float*)d_in[6];
  const float* b_iou = (const float*)d_in[7];
  const float* U_f_w = (const float*)d_in[8];
  const float* U_f_b = (const float*)d_in[9];

  const int Nn = in_sizes[0] / 512;   // 100000
  const int M  = in_sizes[3];         // 99999

  float* out     = (float*)d_out;
  float* h_tilde = out;                         // scratch in h_new half
  float* c_red   = out + (size_t)Nn * 512;      // scratch in c_new half (kept: added in epilogue)

  // ---- workspace arena (aliased regions; lifetimes disjoint) ----
  char* ws = (char*)d_ws;
  size_t sz0 = (size_t)Nn * 1536 * 2;           // region0: g (steps 2-3) then iou (5-6)
  size_t sz1 = (size_t)Nn * 1024 * 2;           // region1: hb (1-2) then Z (4-5)
  size_t off1   = sz0;
  size_t offDeg = off1 + sz1;
  size_t szDeg  = (((size_t)Nn * 4) + 255) & ~(size_t)255;
  size_t offWf  = offDeg + szDeg;
  size_t szWf   = 512 * 512 * 2;
  size_t offWc  = offWf + szWf;
  size_t needed = offWc + (size_t)1536 * 1024 * 2;
  if (ws_size < needed) return;  // workspace too small: fail loudly (zeros out)

  unsigned short* g    = (unsigned short*)(ws);
  unsigned short* iou  = (unsigned short*)(ws);
  unsigned short* hb   = (unsigned short*)(ws + off1);
  unsigned short* Z    = (unsigned short*)(ws + off1);
  int*            deg  = (int*)(ws + offDeg);
  unsigned short* Wf   = (unsigned short*)(ws + offWf);
  unsigned short* Wcat = (unsigned short*)(ws + offWc);

  // zero accumulators (d_out is poisoned once; we must reset every call)
  hipMemsetAsync(d_out, 0, (size_t)out_size * sizeof(float), stream);
  hipMemsetAsync(deg, 0, (size_t)Nn * 4, stream);

  // 1. convert h -> bf16; weights -> bf16
  long long n8h = (long long)Nn * 512 / 8;
  k_f2bf<<<(int)((n8h + 255) / 256), 256, 0, stream>>>(h, hb, n8h);
  k_f2bf<<<(512 * 512 / 8 + 255) / 256, 256, 0, stream>>>(U_f_w, Wf, 512 * 512 / 8);
  k_build_wcat<<<(1536 * 128 + 255) / 256, 256, 0, stream>>>(U_iou, W_iou, Wcat, 1536 * 128);

  // 2. g = sigmoid(hb @ Wf^T + U_f_b)   [N,512]
  dim3 gf(512 / 128, (Nn + 127) / 128);
  k_gemm_bt<1><<<gf, 256, 0, stream>>>(hb, 512, Wf, U_f_b, g, 512, Nn);

  // 3. edge scatter into h_tilde / c_red / deg
  k_scatter<<<(M + 3) / 4, 256, 0, stream>>>(h, c, g, child, parent, h_tilde, c_red, deg, M);

  // 4. Z = has_child ? [h_tilde, 0] : [0, x]   [N,1024] bf16
  k_build_z<<<(int)(((long long)Nn * 64 + 255) / 256), 256, 0, stream>>>(h_tilde, x, deg, Z, Nn);

  // 5. iou = Z @ Wcat^T + b_iou   [N,1536] bf16
  dim3 gi(1536 / 128, (Nn + 127) / 128);
  k_gemm_bt<0><<<gi, 256, 0, stream>>>(Z, 1024, Wcat, b_iou, iou, 1536, Nn);

  // 6. LSTM epilogue -> h_new, c_new (c_red read+overwritten in place)
  k_epilogue<<<(int)(((long long)Nn * 64 + 255) / 256), 256, 0, stream>>>(iou, out, Nn);
}

// Round 2
// 1072.096 us; speedup vs baseline: 3.5009x; 3.5009x over previous
//
#include <hip/hip_runtime.h>
#include <stdint.h>

typedef __bf16 bf16x8 __attribute__((ext_vector_type(8)));
typedef float f32x4 __attribute__((ext_vector_type(4)));
typedef unsigned short ushort8 __attribute__((ext_vector_type(8)));

__device__ __forceinline__ float bf2f(unsigned short u) {
  union { uint32_t i; float f; } v; v.i = ((uint32_t)u) << 16; return v.f;
}
__device__ __forceinline__ unsigned short f2bf(float f) {
  union { uint32_t i; float f; } v; v.f = f;
  uint32_t u = v.i;
  return (unsigned short)((u + 0x7fffu + ((u >> 16) & 1u)) >> 16);
}
__device__ __forceinline__ float sigm(float x) { return 1.0f / (1.0f + __expf(-x)); }
__device__ __forceinline__ float tanh_f(float x) { return 1.0f - 2.0f / (__expf(2.0f * x) + 1.0f); }

__device__ __forceinline__ ushort4 cvt4(float4 a) {
  ushort4 o; o.x = f2bf(a.x); o.y = f2bf(a.y); o.z = f2bf(a.z); o.w = f2bf(a.w); return o;
}

// ---------- fp32 -> bf16 bulk convert, 8 elems/thread ----------
__global__ void k_f2bf(const float* __restrict__ src, unsigned short* __restrict__ dst, long long n8) {
  long long t = (long long)blockIdx.x * blockDim.x + threadIdx.x;
  if (t >= n8) return;
  const float4* s = (const float4*)src + t * 2;
  float4 a = s[0], b = s[1];
  ((ushort4*)dst)[t * 2]     = cvt4(a);
  ((ushort4*)dst)[t * 2 + 1] = cvt4(b);
}

// ---------- build Wcat[1536][1024] = [U_iou | W_iou] in bf16 ----------
__global__ void k_build_wcat(const float* __restrict__ U_iou, const float* __restrict__ W_iou,
                             unsigned short* __restrict__ wcat, int total8) {
  int t = blockIdx.x * blockDim.x + threadIdx.x;
  if (t >= total8) return;
  int row = t >> 7;
  int ch  = t & 127;
  const float* src = (ch < 64) ? (U_iou + (size_t)row * 512 + ch * 8)
                               : (W_iou + (size_t)row * 512 + (ch - 64) * 8);
  const float4* s = (const float4*)src;
  unsigned short* d = wcat + (size_t)row * 1024 + ch * 8;
  ((ushort4*)d)[0] = cvt4(s[0]);
  ((ushort4*)d)[1] = cvt4(s[1]);
}

// ---------- degree histogram ----------
__global__ void k_hist(const int* __restrict__ parent, int* __restrict__ deg, int M) {
  int e = blockIdx.x * blockDim.x + threadIdx.x;
  if (e < M) atomicAdd(&deg[parent[e]], 1);
}

// ---------- scan pass 1: per-block (256) exclusive scan + block sums ----------
__global__ void k_scan1(const int* __restrict__ deg, int* __restrict__ rs,
                        int* __restrict__ bsum, int Nn) {
  __shared__ int tmp[256];
  int t = blockIdx.x * 256 + threadIdx.x;
  int v = (t < Nn) ? deg[t] : 0;
  tmp[threadIdx.x] = v;
  __syncthreads();
#pragma unroll
  for (int d = 1; d < 256; d <<= 1) {
    int a = (threadIdx.x >= d) ? tmp[threadIdx.x - d] : 0;
    __syncthreads();
    tmp[threadIdx.x] += a;
    __syncthreads();
  }
  if (t < Nn) rs[t] = tmp[threadIdx.x] - v;   // exclusive
  if (threadIdx.x == 255) bsum[blockIdx.x] = tmp[255];
}

// ---------- scan pass 2: single block scans block sums (nb <= 512) ----------
__global__ void k_scan2(int* __restrict__ bsum, int nb) {
  __shared__ int tmp[512];
  int i = threadIdx.x;
  int v = (i < nb) ? bsum[i] : 0;
  tmp[i] = v;
  __syncthreads();
#pragma unroll
  for (int d = 1; d < 512; d <<= 1) {
    int a = (i >= d) ? tmp[i - d] : 0;
    __syncthreads();
    tmp[i] += a;
    __syncthreads();
  }
  if (i < nb) bsum[i] = tmp[i] - v;           // exclusive
}

// ---------- scan pass 3: add block offset; also init cursor ----------
__global__ void k_scan3(int* __restrict__ rs, int* __restrict__ cursor,
                        const int* __restrict__ bsum, int Nn) {
  int t = blockIdx.x * 256 + threadIdx.x;
  if (t >= Nn) return;
  int v = rs[t] + bsum[blockIdx.x];
  rs[t] = v;
  cursor[t] = v;
}

// ---------- bucket edges by parent ----------
__global__ void k_fill(const int* __restrict__ parent, const int* __restrict__ child,
                       int* __restrict__ cursor, int* __restrict__ childlist, int M) {
  int e = blockIdx.x * blockDim.x + threadIdx.x;
  if (e >= M) return;
  int p = parent[e];
  int pos = atomicAdd(&cursor[p], 1);
  childlist[pos] = child[e];
}

// ---------- gather-reduce: one wave per parent ----------
// Writes Z[p] = has_child ? [bf16(sum h_ch), 0] : [0, bf16(x_p)]   (K=1024)
// and c_red[p] (f32, only when has_child).
__global__ void k_reduce(const float* __restrict__ h, const float* __restrict__ c,
                         const unsigned short* __restrict__ g, const float* __restrict__ x,
                         const int* __restrict__ rs, const int* __restrict__ childlist,
                         unsigned short* __restrict__ Z, float* __restrict__ c_red,
                         int Nn, int M) {
  int p = blockIdx.x * 4 + (threadIdx.x >> 6);
  if (p >= Nn) return;
  int ln = threadIdx.x & 63;
  int j = ln * 8;
  int start = rs[p];
  int end = (p + 1 < Nn) ? rs[p + 1] : M;
  size_t zb = (size_t)p * 1024 + j;
  if (end > start) {
    float4 ha = {0, 0, 0, 0}, hb = {0, 0, 0, 0};
    float4 ca = {0, 0, 0, 0}, cb4 = {0, 0, 0, 0};
    for (int i = start; i < end; ++i) {
      int ch = childlist[i];
      size_t cbse = (size_t)ch * 512 + j;
      float4 hv0 = *(const float4*)(h + cbse);
      float4 hv1 = *(const float4*)(h + cbse + 4);
      float4 cv0 = *(const float4*)(c + cbse);
      float4 cv1 = *(const float4*)(c + cbse + 4);
      ushort8 gv = *(const ushort8*)(g + cbse);
      ha.x += hv0.x; ha.y += hv0.y; ha.z += hv0.z; ha.w += hv0.w;
      hb.x += hv1.x; hb.y += hv1.y; hb.z += hv1.z; hb.w += hv1.w;
      ca.x += bf2f(gv[0]) * cv0.x; ca.y += bf2f(gv[1]) * cv0.y;
      ca.z += bf2f(gv[2]) * cv0.z; ca.w += bf2f(gv[3]) * cv0.w;
      cb4.x += bf2f(gv[4]) * cv1.x; cb4.y += bf2f(gv[5]) * cv1.y;
      cb4.z += bf2f(gv[6]) * cv1.z; cb4.w += bf2f(gv[7]) * cv1.w;
    }
    ((ushort4*)(Z + zb))[0] = cvt4(ha);
    ((ushort4*)(Z + zb))[1] = cvt4(hb);
    ((ushort4*)(Z + zb + 512))[0] = (ushort4){0, 0, 0, 0};
    ((ushort4*)(Z + zb + 512))[1] = (ushort4){0, 0, 0, 0};
    size_t cr = (size_t)p * 512 + j;
    *(float4*)(c_red + cr)     = ca;
    *(float4*)(c_red + cr + 4) = cb4;
  } else {
    ((ushort4*)(Z + zb))[0] = (ushort4){0, 0, 0, 0};
    ((ushort4*)(Z + zb))[1] = (ushort4){0, 0, 0, 0};
    const float4* s = (const float4*)(x + (size_t)p * 512 + j);
    ((ushort4*)(Z + zb + 512))[0] = cvt4(s[0]);
    ((ushort4*)(Z + zb + 512))[1] = cvt4(s[1]);
  }
}

// ---------- bf16 GEMM, C = act(A @ Bt^T + bias), m97-style 128x128x32 ----------
template <int ACT>
__global__ __launch_bounds__(256)
void k_gemm_bt(const unsigned short* __restrict__ A, int K,
               const unsigned short* __restrict__ Bt,
               const float* __restrict__ bias,
               unsigned short* __restrict__ C, int ldc, int Mrows) {
  __shared__ __align__(16) unsigned short ldsA[128 * 32];
  __shared__ __align__(16) unsigned short ldsB[128 * 32];
  const int tid = threadIdx.x;
  const int wv = tid >> 6, ln = tid & 63;
  const int wr = wv >> 1, wc = wv & 1;
  const int row0 = blockIdx.y * 128;
  const int col0 = blockIdx.x * 128;

  f32x4 acc[4][4] = {};

  for (int k0 = 0; k0 < K; k0 += 32) {
#pragma unroll
    for (int rep = 0; rep < 2; ++rep) {
      int cidx = rep * 256 + wv * 64 + ln;
      int r  = cidx >> 2;
      int kp = (cidx & 3) * 8;
      int ga = row0 + r; if (ga > Mrows - 1) ga = Mrows - 1;
      const unsigned short* srcA = A + (size_t)ga * K + k0 + kp;
      __builtin_amdgcn_global_load_lds(
          (const __attribute__((address_space(1))) void*)(void*)srcA,
          (__attribute__((address_space(3))) void*)(ldsA + (rep * 256 + wv * 64) * 8),
          16, 0, 0);
      const unsigned short* srcB = Bt + (size_t)(col0 + r) * K + k0 + kp;
      __builtin_amdgcn_global_load_lds(
          (const __attribute__((address_space(1))) void*)(void*)srcB,
          (__attribute__((address_space(3))) void*)(ldsB + (rep * 256 + wv * 64) * 8),
          16, 0, 0);
    }
    __syncthreads();

    bf16x8 af[4], bfr[4];
#pragma unroll
    for (int mi = 0; mi < 4; ++mi)
      af[mi] = *(const bf16x8*)(ldsA + (wr * 64 + mi * 16 + (ln & 15)) * 32 + (ln >> 4) * 8);
#pragma unroll
    for (int ni = 0; ni < 4; ++ni)
      bfr[ni] = *(const bf16x8*)(ldsB + (wc * 64 + ni * 16 + (ln & 15)) * 32 + (ln >> 4) * 8);
#pragma unroll
    for (int mi = 0; mi < 4; ++mi)
#pragma unroll
      for (int ni = 0; ni < 4; ++ni)
        acc[mi][ni] = __builtin_amdgcn_mfma_f32_16x16x32_bf16(af[mi], bfr[ni], acc[mi][ni], 0, 0, 0);
    __syncthreads();
  }

#pragma unroll
  for (int mi = 0; mi < 4; ++mi) {
#pragma unroll
    for (int ni = 0; ni < 4; ++ni) {
      int col = col0 + wc * 64 + ni * 16 + (ln & 15);
      float bv = bias[col];
#pragma unroll
      for (int r = 0; r < 4; ++r) {
        int m = row0 + wr * 64 + mi * 16 + (ln >> 4) * 4 + r;
        if (m < Mrows) {
          float v = acc[mi][ni][r] + bv;
          if (ACT == 1) v = sigm(v);
          C[(size_t)m * ldc + col] = f2bf(v);
        }
      }
    }
  }
}

// ---------- LSTM epilogue ----------
__global__ void k_epilogue(const unsigned short* __restrict__ iou,
                           const float* __restrict__ c_red,
                           const int* __restrict__ deg,
                           float* __restrict__ out, int Nn) {
  long long t = (long long)blockIdx.x * blockDim.x + threadIdx.x;
  int n = (int)(t >> 6);
  if (n >= Nn) return;
  int j = ((int)t & 63) * 8;
  size_t ib = (size_t)n * 1536;
  ushort4 iv0 = *(const ushort4*)(iou + ib + j);
  ushort4 iv1 = *(const ushort4*)(iou + ib + j + 4);
  ushort4 ov0 = *(const ushort4*)(iou + ib + 512 + j);
  ushort4 ov1 = *(const ushort4*)(iou + ib + 512 + j + 4);
  ushort4 uv0 = *(const ushort4*)(iou + ib + 1024 + j);
  ushort4 uv1 = *(const ushort4*)(iou + ib + 1024 + j + 4);

  float carr[8] = {0, 0, 0, 0, 0, 0, 0, 0};
  if (deg[n] > 0) {
    size_t cr = (size_t)n * 512 + j;
    float4 cr0 = *(const float4*)(c_red + cr);
    float4 cr1 = *(const float4*)(c_red + cr + 4);
    carr[0] = cr0.x; carr[1] = cr0.y; carr[2] = cr0.z; carr[3] = cr0.w;
    carr[4] = cr1.x; carr[5] = cr1.y; carr[6] = cr1.z; carr[7] = cr1.w;
  }

  float iarr[8] = {bf2f(iv0.x), bf2f(iv0.y), bf2f(iv0.z), bf2f(iv0.w),
                   bf2f(iv1.x), bf2f(iv1.y), bf2f(iv1.z), bf2f(iv1.w)};
  float oarr[8] = {bf2f(ov0.x), bf2f(ov0.y), bf2f(ov0.z), bf2f(ov0.w),
                   bf2f(ov1.x), bf2f(ov1.y), bf2f(ov1.z), bf2f(ov1.w)};
  float uarr[8] = {bf2f(uv0.x), bf2f(uv0.y), bf2f(uv0.z), bf2f(uv0.w),
                   bf2f(uv1.x), bf2f(uv1.y), bf2f(uv1.z), bf2f(uv1.w)};
  float hn[8], cn[8];
#pragma unroll
  for (int q = 0; q < 8; ++q) {
    float cc = sigm(iarr[q]) * tanh_f(uarr[q]) + carr[q];
    cn[q] = cc;
    hn[q] = sigm(oarr[q]) * tanh_f(cc);
  }
  size_t hb = (size_t)n * 512 + j;
  size_t cb = (size_t)Nn * 512 + hb;
  *(float4*)(out + hb)     = make_float4(hn[0], hn[1], hn[2], hn[3]);
  *(float4*)(out + hb + 4) = make_float4(hn[4], hn[5], hn[6], hn[7]);
  *(float4*)(out + cb)     = make_float4(cn[0], cn[1], cn[2], cn[3]);
  *(float4*)(out + cb + 4) = make_float4(cn[4], cn[5], cn[6], cn[7]);
}

extern "C" void kernel_launch(void* const* d_in, const int* in_sizes, int n_in,
                              void* d_out, int out_size, void* d_ws, size_t ws_size,
                              hipStream_t stream) {
  const float* x     = (const float*)d_in[0];
  const float* h     = (const float*)d_in[1];
  const float* c     = (const float*)d_in[2];
  const int* child   = (const int*)d_in[3];
  const int* parent  = (const int*)d_in[4];
  const float* W_iou = (const float*)d_in[5];
  const float* U_iou = (const float*)d_in[6];
  const float* b_iou = (const float*)d_in[7];
  const float* U_f_w = (const float*)d_in[8];
  const float* U_f_b = (const float*)d_in[9];

  const int Nn = in_sizes[0] / 512;   // 100000
  const int M  = in_sizes[3];         // 99999

  float* out = (float*)d_out;

  // ---- workspace arena (aliased regions; lifetimes disjoint) ----
  char* ws = (char*)d_ws;
  size_t sz0 = (size_t)Nn * 1536 * 2;           // region0: g (f-gemm->reduce) then iou
  size_t sz1 = (size_t)Nn * 1024 * 2;           // region1: hb (cvt->f-gemm) then Z
  size_t off1   = sz0;
  size_t offCred= off1 + sz1;
  size_t szCred = (size_t)Nn * 512 * 4;
  size_t offDeg = offCred + szCred;
  size_t szN4   = (((size_t)Nn * 4) + 255) & ~(size_t)255;
  size_t offRs  = offDeg + szN4;
  size_t offCur = offRs + szN4;
  size_t offCl  = offCur + szN4;
  size_t szCl   = (((size_t)M * 4) + 255) & ~(size_t)255;
  size_t offBs  = offCl + szCl;
  size_t szBs   = 512 * 4;
  size_t offWf  = offBs + szBs;
  size_t szWf   = 512 * 512 * 2;
  size_t offWc  = offWf + szWf;
  size_t needed = offWc + (size_t)1536 * 1024 * 2;
  if (ws_size < needed) return;

  unsigned short* g     = (unsigned short*)(ws);
  unsigned short* iou   = (unsigned short*)(ws);
  unsigned short* hbuf  = (unsigned short*)(ws + off1);
  unsigned short* Z     = (unsigned short*)(ws + off1);
  float*          c_red = (float*)(ws + offCred);
  int*            deg   = (int*)(ws + offDeg);
  int*            rs    = (int*)(ws + offRs);
  int*            cursor= (int*)(ws + offCur);
  int*            clist = (int*)(ws + offCl);
  int*            bsum  = (int*)(ws + offBs);
  unsigned short* Wf    = (unsigned short*)(ws + offWf);
  unsigned short* Wcat  = (unsigned short*)(ws + offWc);

  hipMemsetAsync(deg, 0, (size_t)Nn * 4, stream);

  // 1. conversions
  long long n8h = (long long)Nn * 512 / 8;
  k_f2bf<<<(int)((n8h + 255) / 256), 256, 0, stream>>>(h, hbuf, n8h);
  k_f2bf<<<(512 * 512 / 8 + 255) / 256, 256, 0, stream>>>(U_f_w, Wf, 512 * 512 / 8);
  k_build_wcat<<<(1536 * 128 + 255) / 256, 256, 0, stream>>>(U_iou, W_iou, Wcat, 1536 * 128);

  // 2. CSR build
  int nb1 = (Nn + 255) / 256;
  k_hist<<<(M + 255) / 256, 256, 0, stream>>>(parent, deg, M);
  k_scan1<<<nb1, 256, 0, stream>>>(deg, rs, bsum, Nn);
  k_scan2<<<1, 512, 0, stream>>>(bsum, nb1);
  k_scan3<<<nb1, 256, 0, stream>>>(rs, cursor, bsum, Nn);
  k_fill<<<(M + 255) / 256, 256, 0, stream>>>(parent, child, cursor, clist, M);

  // 3. g = sigmoid(hbuf @ Wf^T + U_f_b)   [N,512] bf16
  dim3 gf(512 / 128, (Nn + 127) / 128);
  k_gemm_bt<1><<<gf, 256, 0, stream>>>(hbuf, 512, Wf, U_f_b, g, 512, Nn);

  // 4. gather-reduce -> Z (bf16 [N,1024]) and c_red (f32, has_child only)
  k_reduce<<<(Nn + 3) / 4, 256, 0, stream>>>(h, c, g, x, rs, clist, Z, c_red, Nn, M);

  // 5. iou = Z @ Wcat^T + b_iou   [N,1536] bf16
  dim3 gi(1536 / 128, (Nn + 127) / 128);
  k_gemm_bt<0><<<gi, 256, 0, stream>>>(Z, 1024, Wcat, b_iou, iou, 1536, Nn);

  // 6. epilogue -> h_new, c_new
  k_epilogue<<<(int)(((long long)Nn * 64 + 255) / 256), 256, 0, stream>>>(iou, c_red, deg, out, Nn);
}

// Round 3
// 775.586 us; speedup vs baseline: 4.8393x; 1.3823x over previous
//
#include <hip/hip_runtime.h>
#include <stdint.h>

typedef __bf16 bf16x8 __attribute__((ext_vector_type(8)));
typedef float f32x4 __attribute__((ext_vector_type(4)));
typedef unsigned short ushort8 __attribute__((ext_vector_type(8)));

__device__ __forceinline__ float bf2f(unsigned short u) {
  union { uint32_t i; float f; } v; v.i = ((uint32_t)u) << 16; return v.f;
}
__device__ __forceinline__ unsigned short f2bf(float f) {
  union { uint32_t i; float f; } v; v.f = f;
  uint32_t u = v.i;
  return (unsigned short)((u + 0x7fffu + ((u >> 16) & 1u)) >> 16);
}
__device__ __forceinline__ float sigm(float x) { return 1.0f / (1.0f + __expf(-x)); }
__device__ __forceinline__ float tanh_f(float x) { return 1.0f - 2.0f / (__expf(2.0f * x) + 1.0f); }

__device__ __forceinline__ ushort4 cvt4(float4 a) {
  ushort4 o; o.x = f2bf(a.x); o.y = f2bf(a.y); o.z = f2bf(a.z); o.w = f2bf(a.w); return o;
}

// bijective XCD-aware remap (m204): consecutive wg ids -> same XCD chunk
__device__ __forceinline__ int xcd_swz(int bid, int nwg) {
  int q = nwg >> 3, r = nwg & 7;
  int x = bid & 7, idx = bid >> 3;
  return (x < r ? x * (q + 1) : r * (q + 1) + (x - r) * q) + idx;
}

// ---------- fp32 -> bf16 bulk convert, 8 elems/thread ----------
__global__ void k_f2bf(const float* __restrict__ src, unsigned short* __restrict__ dst, long long n8) {
  long long t = (long long)blockIdx.x * blockDim.x + threadIdx.x;
  if (t >= n8) return;
  const float4* s = (const float4*)src + t * 2;
  float4 a = s[0], b = s[1];
  ((ushort4*)dst)[t * 2]     = cvt4(a);
  ((ushort4*)dst)[t * 2 + 1] = cvt4(b);
}

// ---------- degree histogram ----------
__global__ void k_hist(const int* __restrict__ parent, int* __restrict__ deg, int M) {
  int e = blockIdx.x * blockDim.x + threadIdx.x;
  if (e < M) atomicAdd(&deg[parent[e]], 1);
}

// ---------- packed scan pass 1: low32 = deg scan, high32 = has_child scan ----------
__global__ void k_scan1(const int* __restrict__ deg, unsigned long long* __restrict__ ps,
                        unsigned long long* __restrict__ bsum, int Nn) {
  __shared__ unsigned long long tmp[256];
  int t = blockIdx.x * 256 + threadIdx.x;
  int d = (t < Nn) ? deg[t] : 0;
  unsigned long long v = (unsigned long long)(unsigned)d | ((d > 0) ? (1ull << 32) : 0ull);
  tmp[threadIdx.x] = v;
  __syncthreads();
#pragma unroll
  for (int s = 1; s < 256; s <<= 1) {
    unsigned long long a = (threadIdx.x >= (unsigned)s) ? tmp[threadIdx.x - s] : 0;
    __syncthreads();
    tmp[threadIdx.x] += a;
    __syncthreads();
  }
  if (t < Nn) ps[t] = tmp[threadIdx.x] - v;   // exclusive
  if (threadIdx.x == 255) bsum[blockIdx.x] = tmp[255];
}

// ---------- scan pass 2 + meta: Ni, L0 (leaf slot base), limitLeaf ----------
__global__ void k_scan2(unsigned long long* __restrict__ bsum, int nb,
                        int* __restrict__ meta, int Nn) {
  __shared__ unsigned long long tmp[512];
  int i = threadIdx.x;
  unsigned long long v = (i < nb) ? bsum[i] : 0;
  tmp[i] = v;
  __syncthreads();
#pragma unroll
  for (int s = 1; s < 512; s <<= 1) {
    unsigned long long a = (i >= s) ? tmp[i - s] : 0;
    __syncthreads();
    tmp[i] += a;
    __syncthreads();
  }
  if (i < nb) bsum[i] = tmp[i] - v;           // exclusive
  if (i == 511) {
    int Ni = (int)(tmp[511] >> 32);           // total internal nodes
    int L0 = ((Ni + 127) >> 7) << 7;          // leaf slots start (128-aligned)
    meta[0] = Ni;
    meta[1] = L0;
    meta[2] = L0 + (Nn - Ni);                 // leaf slot end
  }
}

// ---------- scan pass 3: rs/cursor (CSR) + slot (partition) ----------
__global__ void k_scan3(const unsigned long long* __restrict__ ps,
                        const unsigned long long* __restrict__ bsum,
                        const int* __restrict__ meta, const int* __restrict__ deg,
                        int* __restrict__ rs, int* __restrict__ cursor,
                        int* __restrict__ slot, int Nn) {
  int t = blockIdx.x * 256 + threadIdx.x;
  if (t >= Nn) return;
  unsigned long long p = ps[t] + bsum[blockIdx.x];
  int r  = (int)(p & 0xffffffffull);
  int si = (int)(p >> 32);
  rs[t] = r;
  cursor[t] = r;
  slot[t] = (deg[t] > 0) ? si : (meta[1] + (t - si));
}

// ---------- bucket edges by parent ----------
__global__ void k_fill(const int* __restrict__ parent, const int* __restrict__ child,
                       int* __restrict__ cursor, int* __restrict__ childlist, int M) {
  int e = blockIdx.x * blockDim.x + threadIdx.x;
  if (e >= M) return;
  int p = parent[e];
  int pos = atomicAdd(&cursor[p], 1);
  childlist[pos] = child[e];
}

// ---------- gather-reduce: one wave per parent ----------
// internal: Zp[slot] = bf16(sum h_ch)  (K=512), credb[n] = bf16(sum f*c_ch)
// leaf:     Zp[slot] = bf16(x[n])
__global__ void k_reduce(const unsigned short* __restrict__ hbuf, const float* __restrict__ c,
                         const unsigned short* __restrict__ g, const float* __restrict__ x,
                         const int* __restrict__ rs, const int* __restrict__ childlist,
                         const int* __restrict__ slot,
                         unsigned short* __restrict__ Zp, unsigned short* __restrict__ credb,
                         int Nn, int M) {
  int p = blockIdx.x * 4 + (threadIdx.x >> 6);
  if (p >= Nn) return;
  int ln = threadIdx.x & 63;
  int j = ln * 8;
  int start = rs[p];
  int end = (p + 1 < Nn) ? rs[p + 1] : M;
  size_t zb = (size_t)slot[p] * 512 + j;
  if (end > start) {
    float hs[8] = {0, 0, 0, 0, 0, 0, 0, 0};
    float cs[8] = {0, 0, 0, 0, 0, 0, 0, 0};
    for (int i = start; i < end; ++i) {
      int ch = childlist[i];
      size_t cb = (size_t)ch * 512 + j;
      ushort8 hv = *(const ushort8*)(hbuf + cb);
      ushort8 gv = *(const ushort8*)(g + cb);
      float4 cv0 = *(const float4*)(c + cb);
      float4 cv1 = *(const float4*)(c + cb + 4);
      float cvf[8] = {cv0.x, cv0.y, cv0.z, cv0.w, cv1.x, cv1.y, cv1.z, cv1.w};
#pragma unroll
      for (int q = 0; q < 8; ++q) {
        hs[q] += bf2f(hv[q]);
        cs[q] += bf2f(gv[q]) * cvf[q];
      }
    }
    float4 h0 = {hs[0], hs[1], hs[2], hs[3]}, h1 = {hs[4], hs[5], hs[6], hs[7]};
    float4 c0 = {cs[0], cs[1], cs[2], cs[3]}, c1 = {cs[4], cs[5], cs[6], cs[7]};
    ((ushort4*)(Zp + zb))[0] = cvt4(h0);
    ((ushort4*)(Zp + zb))[1] = cvt4(h1);
    size_t cr = (size_t)p * 512 + j;
    ((ushort4*)(credb + cr))[0] = cvt4(c0);
    ((ushort4*)(credb + cr))[1] = cvt4(c1);
  } else {
    const float4* s = (const float4*)(x + (size_t)p * 512 + j);
    float4 x0 = s[0], x1 = s[1];
    ((ushort4*)(Zp + zb))[0] = cvt4(x0);
    ((ushort4*)(Zp + zb))[1] = cvt4(x1);
  }
}

// ---------- bf16 GEMM (f-gate), flat grid + XCD swizzle ----------
template <int ACT>
__global__ __launch_bounds__(256)
void k_gemm_bt(const unsigned short* __restrict__ A, int K,
               const unsigned short* __restrict__ Bt,
               const float* __restrict__ bias,
               unsigned short* __restrict__ C, int ldc, int Mrows, int nbx) {
  __shared__ __align__(16) unsigned short ldsA[128 * 32];
  __shared__ __align__(16) unsigned short ldsB[128 * 32];
  const int tid = threadIdx.x;
  const int wv = tid >> 6, ln = tid & 63;
  const int wr = wv >> 1, wc = wv & 1;
  int wg = xcd_swz(blockIdx.x, gridDim.x);
  int rowp = wg / nbx;
  int colp = wg - rowp * nbx;
  const int row0 = rowp * 128;
  const int col0 = colp * 128;

  f32x4 acc[4][4] = {};

  for (int k0 = 0; k0 < K; k0 += 32) {
#pragma unroll
    for (int rep = 0; rep < 2; ++rep) {
      int cidx = rep * 256 + wv * 64 + ln;
      int r  = cidx >> 2;
      int kp = (cidx & 3) * 8;
      int ga = row0 + r; if (ga > Mrows - 1) ga = Mrows - 1;
      const unsigned short* srcA = A + (size_t)ga * K + k0 + kp;
      __builtin_amdgcn_global_load_lds(
          (const __attribute__((address_space(1))) void*)(void*)srcA,
          (__attribute__((address_space(3))) void*)(ldsA + (rep * 256 + wv * 64) * 8),
          16, 0, 0);
      const unsigned short* srcB = Bt + (size_t)(col0 + r) * K + k0 + kp;
      __builtin_amdgcn_global_load_lds(
          (const __attribute__((address_space(1))) void*)(void*)srcB,
          (__attribute__((address_space(3))) void*)(ldsB + (rep * 256 + wv * 64) * 8),
          16, 0, 0);
    }
    __syncthreads();

    bf16x8 af[4], bfr[4];
#pragma unroll
    for (int mi = 0; mi < 4; ++mi)
      af[mi] = *(const bf16x8*)(ldsA + (wr * 64 + mi * 16 + (ln & 15)) * 32 + (ln >> 4) * 8);
#pragma unroll
    for (int ni = 0; ni < 4; ++ni)
      bfr[ni] = *(const bf16x8*)(ldsB + (wc * 64 + ni * 16 + (ln & 15)) * 32 + (ln >> 4) * 8);
#pragma unroll
    for (int mi = 0; mi < 4; ++mi)
#pragma unroll
      for (int ni = 0; ni < 4; ++ni)
        acc[mi][ni] = __builtin_amdgcn_mfma_f32_16x16x32_bf16(af[mi], bfr[ni], acc[mi][ni], 0, 0, 0);
    __syncthreads();
  }

#pragma unroll
  for (int mi = 0; mi < 4; ++mi) {
#pragma unroll
    for (int ni = 0; ni < 4; ++ni) {
      int col = col0 + wc * 64 + ni * 16 + (ln & 15);
      float bv = bias[col];
#pragma unroll
      for (int r = 0; r < 4; ++r) {
        int m = row0 + wr * 64 + mi * 16 + (ln >> 4) * 4 + r;
        if (m < Mrows) {
          float v = acc[mi][ni][r] + bv;
          if (ACT == 1) v = sigm(v);
          C[(size_t)m * ldc + col] = f2bf(v);
        }
      }
    }
  }
}

// ---------- split iou GEMM: row panel picks U_iou (internal) or W_iou (leaf) ----------
__global__ __launch_bounds__(256)
void k_gemm_iou(const unsigned short* __restrict__ Zp,
                const unsigned short* __restrict__ Ub,
                const unsigned short* __restrict__ Wb,
                const float* __restrict__ bias,
                const int* __restrict__ meta,
                unsigned short* __restrict__ C) {
  __shared__ __align__(16) unsigned short ldsA[128 * 32];
  __shared__ __align__(16) unsigned short ldsB[128 * 32];
  const int K = 512, ldc = 1536;
  const int tid = threadIdx.x;
  const int wv = tid >> 6, ln = tid & 63;
  const int wr = wv >> 1, wc = wv & 1;
  int wg = xcd_swz(blockIdx.x, gridDim.x);
  int rowp = wg / 12;
  int colp = wg - rowp * 12;
  const int row0 = rowp * 128;
  const int col0 = colp * 128;

  const int Ni = meta[0], L0 = meta[1], lim2 = meta[2];
  const bool internal = row0 < L0;        // internal panels never straddle Ni (L0 128-aligned)
  const int limit = internal ? Ni : lim2;
  if (row0 >= limit) return;              // beyond leaf end (uniform per block)
  const unsigned short* __restrict__ Bt = internal ? Ub : Wb;

  f32x4 acc[4][4] = {};

  for (int k0 = 0; k0 < K; k0 += 32) {
#pragma unroll
    for (int rep = 0; rep < 2; ++rep) {
      int cidx = rep * 256 + wv * 64 + ln;
      int r  = cidx >> 2;
      int kp = (cidx & 3) * 8;
      int ga = row0 + r; if (ga > limit - 1) ga = limit - 1;
      const unsigned short* srcA = Zp + (size_t)ga * K + k0 + kp;
      __builtin_amdgcn_global_load_lds(
          (const __attribute__((address_space(1))) void*)(void*)srcA,
          (__attribute__((address_space(3))) void*)(ldsA + (rep * 256 + wv * 64) * 8),
          16, 0, 0);
      const unsigned short* srcB = Bt + (size_t)(col0 + r) * K + k0 + kp;
      __builtin_amdgcn_global_load_lds(
          (const __attribute__((address_space(1))) void*)(void*)srcB,
          (__attribute__((address_space(3))) void*)(ldsB + (rep * 256 + wv * 64) * 8),
          16, 0, 0);
    }
    __syncthreads();

    bf16x8 af[4], bfr[4];
#pragma unroll
    for (int mi = 0; mi < 4; ++mi)
      af[mi] = *(const bf16x8*)(ldsA + (wr * 64 + mi * 16 + (ln & 15)) * 32 + (ln >> 4) * 8);
#pragma unroll
    for (int ni = 0; ni < 4; ++ni)
      bfr[ni] = *(const bf16x8*)(ldsB + (wc * 64 + ni * 16 + (ln & 15)) * 32 + (ln >> 4) * 8);
#pragma unroll
    for (int mi = 0; mi < 4; ++mi)
#pragma unroll
      for (int ni = 0; ni < 4; ++ni)
        acc[mi][ni] = __builtin_amdgcn_mfma_f32_16x16x32_bf16(af[mi], bfr[ni], acc[mi][ni], 0, 0, 0);
    __syncthreads();
  }

#pragma unroll
  for (int mi = 0; mi < 4; ++mi) {
#pragma unroll
    for (int ni = 0; ni < 4; ++ni) {
      int col = col0 + wc * 64 + ni * 16 + (ln & 15);
      float bv = bias[col];
#pragma unroll
      for (int r = 0; r < 4; ++r) {
        int m = row0 + wr * 64 + mi * 16 + (ln >> 4) * 4 + r;
        if (m < limit) {
          C[(size_t)m * ldc + col] = f2bf(acc[mi][ni][r] + bv);
        }
      }
    }
  }
}

// ---------- LSTM epilogue (slot-indirect iou read) ----------
__global__ void k_epilogue(const unsigned short* __restrict__ iou,
                           const unsigned short* __restrict__ credb,
                           const int* __restrict__ slot,
                           const int* __restrict__ meta,
                           float* __restrict__ out, int Nn) {
  long long t = (long long)blockIdx.x * blockDim.x + threadIdx.x;
  int n = (int)(t >> 6);
  if (n >= Nn) return;
  int j = ((int)t & 63) * 8;
  int sl = slot[n];
  int Ni = meta[0];
  size_t ib = (size_t)sl * 1536;
  ushort4 iv0 = *(const ushort4*)(iou + ib + j);
  ushort4 iv1 = *(const ushort4*)(iou + ib + j + 4);
  ushort4 ov0 = *(const ushort4*)(iou + ib + 512 + j);
  ushort4 ov1 = *(const ushort4*)(iou + ib + 512 + j + 4);
  ushort4 uv0 = *(const ushort4*)(iou + ib + 1024 + j);
  ushort4 uv1 = *(const ushort4*)(iou + ib + 1024 + j + 4);

  float carr[8] = {0, 0, 0, 0, 0, 0, 0, 0};
  if (sl < Ni) {
    size_t cr = (size_t)n * 512 + j;
    ushort4 c0 = *(const ushort4*)(credb + cr);
    ushort4 c1 = *(const ushort4*)(credb + cr + 4);
    carr[0] = bf2f(c0.x); carr[1] = bf2f(c0.y); carr[2] = bf2f(c0.z); carr[3] = bf2f(c0.w);
    carr[4] = bf2f(c1.x); carr[5] = bf2f(c1.y); carr[6] = bf2f(c1.z); carr[7] = bf2f(c1.w);
  }

  float iarr[8] = {bf2f(iv0.x), bf2f(iv0.y), bf2f(iv0.z), bf2f(iv0.w),
                   bf2f(iv1.x), bf2f(iv1.y), bf2f(iv1.z), bf2f(iv1.w)};
  float oarr[8] = {bf2f(ov0.x), bf2f(ov0.y), bf2f(ov0.z), bf2f(ov0.w),
                   bf2f(ov1.x), bf2f(ov1.y), bf2f(ov1.z), bf2f(ov1.w)};
  float uarr[8] = {bf2f(uv0.x), bf2f(uv0.y), bf2f(uv0.z), bf2f(uv0.w),
                   bf2f(uv1.x), bf2f(uv1.y), bf2f(uv1.z), bf2f(uv1.w)};
  float hn[8], cn[8];
#pragma unroll
  for (int q = 0; q < 8; ++q) {
    float cc = sigm(iarr[q]) * tanh_f(uarr[q]) + carr[q];
    cn[q] = cc;
    hn[q] = sigm(oarr[q]) * tanh_f(cc);
  }
  size_t hb = (size_t)n * 512 + j;
  size_t cb = (size_t)Nn * 512 + hb;
  *(float4*)(out + hb)     = make_float4(hn[0], hn[1], hn[2], hn[3]);
  *(float4*)(out + hb + 4) = make_float4(hn[4], hn[5], hn[6], hn[7]);
  *(float4*)(out + cb)     = make_float4(cn[0], cn[1], cn[2], cn[3]);
  *(float4*)(out + cb + 4) = make_float4(cn[4], cn[5], cn[6], cn[7]);
}

extern "C" void kernel_launch(void* const* d_in, const int* in_sizes, int n_in,
                              void* d_out, int out_size, void* d_ws, size_t ws_size,
                              hipStream_t stream) {
  const float* x     = (const float*)d_in[0];
  const float* h     = (const float*)d_in[1];
  const float* c     = (const float*)d_in[2];
  const int* child   = (const int*)d_in[3];
  const int* parent  = (const int*)d_in[4];
  const float* W_iou = (const float*)d_in[5];
  const float* U_iou = (const float*)d_in[6];
  const float* b_iou = (const float*)d_in[7];
  const float* U_f_w = (const float*)d_in[8];
  const float* U_f_b = (const float*)d_in[9];

  const int Nn = in_sizes[0] / 512;   // 100000
  const int M  = in_sizes[3];         // 99999

  float* out = (float*)d_out;

  // ---- workspace arena ----
  char* ws = (char*)d_ws;
  auto al = [](size_t v) { return (v + 255) & ~(size_t)255; };
  size_t sz0    = al((size_t)(Nn + 256) * 1536 * 2);  // region0: g (bf16 N*512) then iou (slot rows)
  size_t offZp  = sz0;
  size_t szZp   = al((size_t)(Nn + 256) * 512 * 2);
  size_t offHb  = offZp + szZp;
  size_t szHb   = al((size_t)Nn * 512 * 2);
  size_t offCr  = offHb + szHb;
  size_t szCr   = al((size_t)Nn * 512 * 2);
  size_t offDeg = offCr + szCr;
  size_t szN4   = al((size_t)Nn * 4);
  size_t offRs  = offDeg + szN4;
  size_t offCur = offRs + szN4;
  size_t offSl  = offCur + szN4;
  size_t offPs  = offSl + szN4;
  size_t szPs   = al((size_t)Nn * 8);
  size_t offCl  = offPs + szPs;
  size_t szCl   = al((size_t)M * 4);
  size_t offBs  = offCl + szCl;
  size_t szBs   = al(512 * 8);
  size_t offMt  = offBs + szBs;
  size_t szMt   = 256;
  size_t offWf  = offMt + szMt;
  size_t szWf   = al(512 * 512 * 2);
  size_t offUb  = offWf + szWf;
  size_t szUw   = al((size_t)1536 * 512 * 2);
  size_t offWb  = offUb + szUw;
  size_t needed = offWb + szUw;
  if (ws_size < needed) return;

  unsigned short* g     = (unsigned short*)(ws);
  unsigned short* iou   = (unsigned short*)(ws);
  unsigned short* Zp    = (unsigned short*)(ws + offZp);
  unsigned short* hbuf  = (unsigned short*)(ws + offHb);
  unsigned short* credb = (unsigned short*)(ws + offCr);
  int*            deg   = (int*)(ws + offDeg);
  int*            rs    = (int*)(ws + offRs);
  int*            cursor= (int*)(ws + offCur);
  int*            slot  = (int*)(ws + offSl);
  unsigned long long* ps   = (unsigned long long*)(ws + offPs);
  int*            clist = (int*)(ws + offCl);
  unsigned long long* bsum = (unsigned long long*)(ws + offBs);
  int*            meta  = (int*)(ws + offMt);
  unsigned short* Wf    = (unsigned short*)(ws + offWf);
  unsigned short* Ub    = (unsigned short*)(ws + offUb);
  unsigned short* Wb    = (unsigned short*)(ws + offWb);

  hipMemsetAsync(deg, 0, (size_t)Nn * 4, stream);

  // 1. conversions
  long long n8h = (long long)Nn * 512 / 8;
  k_f2bf<<<(int)((n8h + 255) / 256), 256, 0, stream>>>(h, hbuf, n8h);
  k_f2bf<<<(512 * 512 / 8 + 255) / 256, 256, 0, stream>>>(U_f_w, Wf, 512 * 512 / 8);
  k_f2bf<<<(1536 * 512 / 8 + 255) / 256, 256, 0, stream>>>(U_iou, Ub, 1536 * 512 / 8);
  k_f2bf<<<(1536 * 512 / 8 + 255) / 256, 256, 0, stream>>>(W_iou, Wb, 1536 * 512 / 8);

  // 2. CSR + partition build (one packed scan)
  int nb1 = (Nn + 255) / 256;
  k_hist<<<(M + 255) / 256, 256, 0, stream>>>(parent, deg, M);
  k_scan1<<<nb1, 256, 0, stream>>>(deg, ps, bsum, Nn);
  k_scan2<<<1, 512, 0, stream>>>(bsum, nb1, meta, Nn);
  k_scan3<<<nb1, 256, 0, stream>>>(ps, bsum, meta, deg, rs, cursor, slot, Nn);
  k_fill<<<(M + 255) / 256, 256, 0, stream>>>(parent, child, cursor, clist, M);

  // 3. g = sigmoid(hbuf @ Wf^T + U_f_b)   [N,512] bf16
  int nbyF = (Nn + 127) / 128;
  k_gemm_bt<1><<<nbyF * 4, 256, 0, stream>>>(hbuf, 512, Wf, U_f_b, g, 512, Nn, 4);

  // 4. gather-reduce -> Zp (bf16 [slot,512]) and credb (bf16, internal only)
  k_reduce<<<(Nn + 3) / 4, 256, 0, stream>>>(hbuf, c, g, x, rs, clist, slot, Zp, credb, Nn, M);

  // 5. iou[slot] = Zp @ (U_iou|W_iou)^T + b_iou   [slot,1536] bf16, K=512
  int nbyI = (Nn >> 7) + 2;
  k_gemm_iou<<<nbyI * 12, 256, 0, stream>>>(Zp, Ub, Wb, b_iou, meta, iou);

  // 6. epilogue -> h_new, c_new
  k_epilogue<<<(int)(((long long)Nn * 64 + 255) / 256), 256, 0, stream>>>(iou, credb, slot, meta, out, Nn);
}